// Round 9
// baseline (1217.954 us; speedup 1.0000x reference)
//
#include <hip/hip_runtime.h>

// Problem constants
#define NROWS   16384      // 16*32*32 flattened (b,h,w) rows
#define KCODES  8192
#define CDIM    256
#define HWS     1024       // 32*32
#define BSTRIDE 262144     // 256*1024 floats per batch in z / out

// Workspace layout (float-unit offsets) -- 4 slices
#define WS_AN   0                         // ||x||^2 per row       [16384]
#define WS_CE   16384                     // ||e||^2 per code      [8192]
#define WS_CD   24576                     // cand dist [n*4+slice] [65536]
#define WS_CI   90112                     // cand idx  (int)       [65536]
#define WS_IDX  155648                    // final idx (int)       [16384]
#define WS_LOSS 172032                    // loss accumulator      [1]

// -------- row norms, replicating numpy pairwise_sum order exactly --------
__global__ void rownorm_z_k(const float* __restrict__ z, float* __restrict__ An) {
#pragma clang fp contract(off)
  int n = blockIdx.x * 256 + threadIdx.x;                    // 16384 threads
  const float* base = z + ((size_t)(n >> 10)) * BSTRIDE + (n & 1023);
  float hs[2];
  for (int h = 0; h < 2; ++h) {
    float r[8];
#pragma unroll
    for (int j = 0; j < 8; ++j) { float v = base[(size_t)(h * 128 + j) * HWS]; r[j] = v * v; }
    for (int m = 1; m < 16; ++m) {
#pragma unroll
      for (int j = 0; j < 8; ++j) { float v = base[(size_t)(h * 128 + m * 8 + j) * HWS]; r[j] += v * v; }
    }
    hs[h] = ((r[0] + r[1]) + (r[2] + r[3])) + ((r[4] + r[5]) + (r[6] + r[7]));
  }
  An[n] = hs[0] + hs[1];
}

__global__ void rownorm_e_k(const float* __restrict__ emb, float* __restrict__ Ce) {
#pragma clang fp contract(off)
  int n = blockIdx.x * 256 + threadIdx.x;                    // 8192 threads
  const float* base = emb + (size_t)n * CDIM;
  float hs[2];
  for (int h = 0; h < 2; ++h) {
    float r[8];
#pragma unroll
    for (int j = 0; j < 8; ++j) { float v = base[h * 128 + j]; r[j] = v * v; }
    for (int m = 1; m < 16; ++m) {
#pragma unroll
      for (int j = 0; j < 8; ++j) { float v = base[h * 128 + m * 8 + j]; r[j] += v * v; }
    }
    hs[h] = ((r[0] + r[1]) + (r[2] + r[3])) + ((r[4] + r[5]) + (r[6] + r[7]));
  }
  Ce[n] = hs[0] + hs[1];
}

// -------- fused distance + argmin --------
// 512 blocks = 128 row-tiles (128 rows) x 4 code-slices (2048 codes each)
// = exactly one generation at 2 blocks/CU (64 KB LDS each).
// 256 threads = 16 tx x 16 ty. Micro-tile 8 rows x 8 codes. 32-c superchunks.
//
// DOUBLE-BUFFERED LDS, one barrier per superstep (round-8 lesson: the
// 2-barrier superstep serialized [store + lgkmcnt(0)] block-wide 128x, and
// co-resident blocks run in lockstep so the serial phases resonate; that,
// not LDS throughput, was the 2.15x-over-floor gap). Stores for superstep
// s+1 go to buf^1 mid-compute of buf -> store cycles + vmcnt hide under FMA.
// Bank layout unchanged from round 8 (128B rows + 3-bit XOR swizzle):
//   A reads 1-phase, B reads 2-phase, A stores 2-way, B stores 8-phase floor.
// Registers: acc 64 + bf 32 + prefetch 32 (live g0-2) + best/bidx 16 + addr
// ~16 ~= 165 -> 2 waves/SIMD (budget 256, no squeeze pressure). WRITE_SIZE
// is the spill tripwire (rounds 1-2: allocator squeeze -> GBs of scratch).
__global__ void __launch_bounds__(256)
vq_argmin_k(const float* __restrict__ z, const float* __restrict__ emb,
            const float* __restrict__ An, const float* __restrict__ Ce,
            float* __restrict__ cand_d, int* __restrict__ cand_i) {
  __shared__ float smem[16384];    // 64 KB: buf p at p*8192; As=+0, Bs=+4096

  const int t  = threadIdx.x;
  const int tx = t & 15;           // code group (8 codes, stride 16)
  const int ty = t >> 4;           // row group (8 consecutive rows)
  const int tile  = blockIdx.x >> 2;
  const int slice = blockIdx.x & 3;
  const int rbase = tile * 128;    // never crosses the 1024-hw batch edge
  const int k0    = slice * 2048;

  const float* zb = z + ((size_t)(rbase >> 10)) * BSTRIDE + (rbase & 1023);

  float best[8];
  int   bidx[8];
#pragma unroll
  for (int ri = 0; ri < 8; ++ri) { best[ri] = 3.4028235e38f; bidx[ri] = 0; }

  float acc[8][8];
#pragma unroll
  for (int ri = 0; ri < 8; ++ri)
#pragma unroll
    for (int ci = 0; ci < 8; ++ci) acc[ri][ci] = 0.f;

  // staging thread mappings (round-8 layout, unchanged)
  const int a_c   = t >> 4;         // stages c_locals {a_c, a_c+16}, 8 rows each
  const int a_hw  = (t & 15) * 8;   // 8 consecutive rows
  const int a_swr = (t & 15) & 7;   // (row>>3)&7 for all 8 staged rows
  const int a_wi  = a_c & 3;
  const int a_kg1 = a_c >> 2;
  const int acol1 = ((a_kg1 ^ a_swr) << 2) | a_wi;
  const int acol2 = (((a_kg1 + 4) ^ a_swr) << 2) | a_wi;
  const int b_code = t >> 1;        // code 0..127
  const int b_cb   = (t & 1) * 16;  // c_local base 0 or 16
  const int b_swr  = (t >> 1) & 7;  // code&7
  const int b_kg0  = b_cb >> 2;     // 0 or 4

  const int rd_a_sw = ty & 7;
  const int rd_b_sw = tx & 7;
  const int aRowBase = (ty * 8) << 5;   // A read row base (floats)
  const int bColBase = tx << 5;         // B read base (floats)

  // superstep s: kc = s>>3 (codes kbase=k0+kc*128), sc = s&7 (c = sc*32..+31)
  float4 pa0, pa1, pa2, pa3, pb0, pb1, pb2, pb3;

  auto issue_loads = [&](int s) {
    const int sc = s & 7;
    const int kc = s >> 3;
    const float* zsrc = zb + (size_t)(sc * 32 + a_c) * HWS + a_hw;
    pa0 = *(const float4*)(zsrc);
    pa1 = *(const float4*)(zsrc + 4);
    pa2 = *(const float4*)(zsrc + 16 * HWS);
    pa3 = *(const float4*)(zsrc + 16 * HWS + 4);
    const float* bsrc = emb + (size_t)(k0 + kc * 128 + b_code) * CDIM + sc * 32 + b_cb;
    pb0 = *(const float4*)(bsrc);
    pb1 = *(const float4*)(bsrc + 4);
    pb2 = *(const float4*)(bsrc + 8);
    pb3 = *(const float4*)(bsrc + 12);
  };

  auto stage = [&](float* Ad, float* Bd) {
    const float va0[8] = {pa0.x, pa0.y, pa0.z, pa0.w, pa1.x, pa1.y, pa1.z, pa1.w};
    const float va1[8] = {pa2.x, pa2.y, pa2.z, pa2.w, pa3.x, pa3.y, pa3.z, pa3.w};
#pragma unroll
    for (int j = 0; j < 8; ++j) {
      const int rb = (a_hw + j) << 5;
      Ad[rb + acol1] = va0[j];
      Ad[rb + acol2] = va1[j];
    }
    const int bb = b_code << 5;
    *(float4*)&Bd[bb + (((b_kg0 + 0) ^ b_swr) << 2)] = pb0;
    *(float4*)&Bd[bb + (((b_kg0 + 1) ^ b_swr) << 2)] = pb1;
    *(float4*)&Bd[bb + (((b_kg0 + 2) ^ b_swr) << 2)] = pb2;
    *(float4*)&Bd[bb + (((b_kg0 + 3) ^ b_swr) << 2)] = pb3;
  };

  // prologue: fill buffer 0 with superstep 0
  issue_loads(0);
  stage(smem, smem + 4096);
  __syncthreads();

#pragma unroll 1
  for (int s = 0; s < 128; ++s) {
    const float* Acur = smem + ((s & 1) << 13);
    const float* Bcur = Acur + 4096;
    float* Anxt = smem + (((s + 1) & 1) << 13);
    float* Bnxt = Anxt + 4096;
    const bool has_next = (s < 127);

    if (has_next) issue_loads(s + 1);     // in flight across g0..g2

    auto compute_g = [&](int g) {
      float4 bf[8];
#pragma unroll
      for (int ci = 0; ci < 8; ++ci)
        bf[ci] = *(const float4*)&Bcur[bColBase + (ci << 9) + ((g ^ rd_b_sw) << 2)];
#pragma unroll
      for (int ri = 0; ri < 8; ++ri) {
        const float4 a = *(const float4*)&Acur[aRowBase + (ri << 5) + ((g ^ rd_a_sw) << 2)];
#pragma unroll
        for (int ci = 0; ci < 8; ++ci) {
          // 4-k groups ascending, k3-first nesting: identical to rounds 1-8
          acc[ri][ci] = fmaf(a.x, bf[ci].x, fmaf(a.y, bf[ci].y,
                        fmaf(a.z, bf[ci].z, fmaf(a.w, bf[ci].w, acc[ri][ci]))));
        }
      }
    };

#pragma unroll
    for (int g = 0; g < 3; ++g) compute_g(g);

    if (has_next) stage(Anxt, Bnxt);      // other buffer: no WAR, no barrier

#pragma unroll
    for (int g = 3; g < 8; ++g) compute_g(g);

    if ((s & 7) == 7) {
      // fold per kc: dist = (A - 2*dot) + C, np's elementwise fp32 rounding.
      // thread's codes ascend with ci (tx + ci*16) + strict < -> lowest-index
      // min within thread; cross-thread/slice merges compare indices.
      const int kc = s >> 3;
      const int kkb = k0 + kc * 128 + tx;
      float cearr[8];
#pragma unroll
      for (int ci = 0; ci < 8; ++ci) cearr[ci] = Ce[kkb + ci * 16];
#pragma unroll
      for (int ri = 0; ri < 8; ++ri) {
        const float Ar = An[rbase + ty * 8 + ri];
#pragma unroll
        for (int ci = 0; ci < 8; ++ci) {
          const float d = (Ar - 2.0f * acc[ri][ci]) + cearr[ci];
          if (d < best[ri]) { best[ri] = d; bidx[ri] = kkb + ci * 16; }
          acc[ri][ci] = 0.f;
        }
      }
    }
    __syncthreads();                      // single barrier per superstep
  }

  // cross-thread argmin per row (tie -> lower absolute index); alias smem
  float* redd = smem;              // [128][16]
  int*   redi = (int*)(smem + 2048);
#pragma unroll
  for (int ri = 0; ri < 8; ++ri) {
    redd[(ty * 8 + ri) * 16 + tx] = best[ri];
    redi[(ty * 8 + ri) * 16 + tx] = bidx[ri];
  }
  __syncthreads();
  if (t < 128) {
    float bd = redd[t * 16];
    int   bi = redi[t * 16];
    for (int j = 1; j < 16; ++j) {
      const float d  = redd[t * 16 + j];
      const int   i2 = redi[t * 16 + j];
      if (d < bd || (d == bd && i2 < bi)) { bd = d; bi = i2; }
    }
    const int n = rbase + t;
    cand_d[n * 4 + slice] = bd;
    cand_i[n * 4 + slice] = bi;
  }
}

// -------- merge the 4 code-slices (tie -> lower index) --------
__global__ void vq_merge_k(const float* __restrict__ cand_d, const int* __restrict__ cand_i,
                           int* __restrict__ idx_final, float* __restrict__ idxf_out) {
  const int n = blockIdx.x * 256 + threadIdx.x;   // 16384
  float bd = cand_d[n * 4];
  int   bi = cand_i[n * 4];
#pragma unroll
  for (int s = 1; s < 4; ++s) {
    const float d  = cand_d[n * 4 + s];
    const int   i2 = cand_i[n * 4 + s];
    if (d < bd || (d == bd && i2 < bi)) { bd = d; bi = i2; }
  }
  idx_final[n] = bi;
  idxf_out[n] = (float)bi;
}

// -------- gather quantized, write straight-through output, accumulate loss ----
// quantized_st = z + (q - z) in fp32 (matches np rounding; != q exactly).
__launch_bounds__(256)
__global__ void vq_gather_loss_k(const float* __restrict__ z, const float* __restrict__ emb,
                                 const int* __restrict__ idx_final,
                                 float* __restrict__ qout, float* __restrict__ loss_acc) {
  __shared__ float Qs[32 * 260];
  __shared__ int   kidx[32];
  __shared__ float warp_s[4];
  const int t = threadIdx.x;
  const int rbase = blockIdx.x * 32;
  if (t < 32) kidx[t] = idx_final[rbase + t];
  __syncthreads();
  {
    const int r = t >> 3, cp = t & 7;
    const float4* er = (const float4*)(emb + (size_t)kidx[r] * CDIM);
#pragma unroll
    for (int j = 0; j < 8; ++j) {
      const int c4 = cp + j * 8;
      const float4 v = er[c4];
      *(float4*)&Qs[r * 260 + c4 * 4] = v;
    }
  }
  __syncthreads();
  const int b = rbase >> 10, hw0 = rbase & 1023;
  const float* zb = z + (size_t)b * BSTRIDE + hw0;
  float* qb = qout + (size_t)b * BSTRIDE + hw0;
  float s = 0.f;
  const int hwl = t & 31, cg = t >> 5;
  for (int i = 0; i < 32; ++i) {
    const int c = cg * 32 + i;
    const float q  = Qs[hwl * 260 + c];
    const size_t off = (size_t)c * HWS + hwl;
    const float zv = zb[off];
    const float d  = q - zv;
    qb[off] = zv + d;          // straight-through value, np rounding
    s += d * d;
  }
  for (int off = 32; off; off >>= 1) s += __shfl_down(s, off, 64);
  if ((t & 63) == 0) warp_s[t >> 6] = s;
  __syncthreads();
  if (t == 0) atomicAdd(loss_acc, warp_s[0] + warp_s[1] + warp_s[2] + warp_s[3]);
}

__global__ void vq_finalize_k(const float* __restrict__ loss_acc, float* __restrict__ out_loss) {
  const float m = loss_acc[0] * (1.0f / 4194304.0f);
  out_loss[0] = m;          // codebook_loss
  out_loss[1] = 0.25f * m;  // commitment_loss (BETA * same mean)
}

extern "C" void kernel_launch(void* const* d_in, const int* in_sizes, int n_in,
                              void* d_out, int out_size, void* d_ws, size_t ws_size,
                              hipStream_t stream) {
  (void)in_sizes; (void)n_in; (void)out_size; (void)ws_size;
  const float* z   = (const float*)d_in[0];
  const float* emb = (const float*)d_in[1];
  float* out      = (float*)d_out;
  float* q_out    = out;                 // [16,256,32,32]
  float* loss_out = out + 4194304;       // 2 scalars
  float* idxf_out = out + 4194306;       // [16,32,32] as float

  float* ws       = (float*)d_ws;
  float* An       = ws + WS_AN;
  float* Ce       = ws + WS_CE;
  float* cand_d   = ws + WS_CD;
  int*   cand_i   = (int*)(ws + WS_CI);
  int*   idx_fin  = (int*)(ws + WS_IDX);
  float* loss_acc = ws + WS_LOSS;

  hipMemsetAsync(loss_acc, 0, sizeof(float), stream);
  rownorm_z_k<<<64, 256, 0, stream>>>(z, An);
  rownorm_e_k<<<32, 256, 0, stream>>>(emb, Ce);
  vq_argmin_k<<<512, 256, 0, stream>>>(z, emb, An, Ce, cand_d, cand_i);
  vq_merge_k<<<64, 256, 0, stream>>>(cand_d, cand_i, idx_fin, idxf_out);
  vq_gather_loss_k<<<512, 256, 0, stream>>>(z, emb, idx_fin, q_out, loss_acc);
  vq_finalize_k<<<1, 1, 0, stream>>>(loss_acc, loss_out);
}